// Round 6
// baseline (88.045 us; speedup 1.0000x reference)
//
#include <hip/hip_runtime.h>
#include <math.h>

// Problem constants (fixed by setup_inputs): N src points, M targets, D=3.
constexpr int N_SRC = 16384;
constexpr int M_TAR = 16384;

// R6: R5's 4.5-VALU-op/pair inner loop, but with ILP headroom to hide LDS
// latency. R5 post-mortem: __launch_bounds__(1024,8) capped VGPR at 64, so
// ds_read_b128 could not be hoisted -> ~120cyc LDS latency exposed per body
// (barriers keep waves in lockstep, TLP didn't cover it). Fix: 512-thread
// blocks, __launch_bounds__(512,4) -> 128 VGPR cap, still 2 blocks/CU
// (LDS-capped, 64KB tile) = 16 waves/CU. Explicit 1-body software pipeline:
// prefetch next 2 sources (registers) while computing current body's
// 72 VALU ops (144 cyc > 120 cyc LDS latency).
//   thread owns 8 targets (g=tid&3), chunk = tid>>2 in [0,128)
//   source j = row*128 + chunk, row in [0,128) -> 7-bit mantissa embed
//   per pair: 3 v_fma_f32 + 1 v_and_or_b32 + 0.5 v_min3_f32
constexpr int BLOCKS = M_TAR / 32;   // 512 blocks = exactly 2/CU, one pass
constexpr int TPB = 512;             // 8 waves
constexpr int CHUNKS = 128;          // tid>>2
constexpr int TILE = 4096;           // sources per LDS tile (64 KB float4)
constexpr int TILES = N_SRC / TILE;  // 4
constexpr int BODIES = TILE / CHUNKS / 2;  // 16 two-source bodies per tile

__global__ void zero_out(float* __restrict__ out) {
    if (threadIdx.x == 0) out[0] = 0.0f;  // d_out poisoned 0xAA each launch
}

// (t & mask_v) | row_s — mask in VGPR, uniform row rides the one SGPR slot
__device__ __forceinline__ float embed_ao(float t, unsigned mask_v, unsigned row_s) {
    float r;
    asm("v_and_or_b32 %0, %1, %2, %3"
        : "=v"(r) : "v"(t), "v"(mask_v), "s"(row_s));
    return r;
}
// best = min(best, e0, e1) in one instruction (inputs never NaN here)
__device__ __forceinline__ void min3(float& b, float e0, float e1) {
    asm("v_min3_f32 %0, %1, %2, %3"
        : "=v"(b) : "v"(b), "v"(e0), "v"(e1));
}

__global__ __launch_bounds__(TPB, 4) void nn7(const float* __restrict__ src,
                                              const float* __restrict__ tar,
                                              float* __restrict__ out) {
    __shared__ float4 tile[TILE];  // 64 KB; reused as (fv, fj) in the tail

    const int tid   = threadIdx.x;
    const int g     = tid & 3;
    const int chunk = tid >> 2;    // 0..127
    const int tbase = blockIdx.x * 32;

    // 8 targets/thread, premultiplied by -2 so ||s||^2 folds into the fma chain
    float txm2[8], tym2[8], tzm2[8], best[8];
#pragma unroll
    for (int k = 0; k < 8; ++k) {
        int T = tbase + g + 4 * k;
        txm2[k] = -2.0f * tar[3 * T + 0];
        tym2[k] = -2.0f * tar[3 * T + 1];
        tzm2[k] = -2.0f * tar[3 * T + 2];
        best[k] = INFINITY;
    }

    unsigned mask_v = 0xFFFFFF80u;  // keep low 7 bits free for the row index

    for (int tl = 0; tl < TILES; ++tl) {
        // ---- stage tile: 4096 sources as (x,y,z,||s||^2)
#pragma unroll
        for (int r = 0; r < TILE / TPB; ++r) {
            int p  = tid + r * TPB;
            int j3 = 3 * (tl * TILE + p);
            float x = src[j3 + 0], y = src[j3 + 1], z = src[j3 + 2];
            tile[p] = make_float4(x, y, z, fmaf(x, x, fmaf(y, y, z * z)));
        }
        __syncthreads();

        // ---- scan, software-pipelined one body deep
        float4 s0 = tile[0 * CHUNKS + chunk];
        float4 s1 = tile[1 * CHUNKS + chunk];
#pragma unroll
        for (int i = 0; i < BODIES; ++i) {
            float4 n0, n1;
            if (i + 1 < BODIES) {           // compile-time after unroll
                n0 = tile[(2 * i + 2) * CHUNKS + chunk];
                n1 = tile[(2 * i + 3) * CHUNKS + chunk];
            }
            unsigned row0 = (unsigned)(tl * 2 * BODIES + 2 * i);      // uniform
            unsigned row1 = row0 + 1;                                 // uniform
#pragma unroll
            for (int k = 0; k < 8; ++k) {
                float t0 = fmaf(s0.z, tzm2[k], s0.w);
                t0 = fmaf(s0.y, tym2[k], t0);
                t0 = fmaf(s0.x, txm2[k], t0);
                float t1 = fmaf(s1.z, tzm2[k], s1.w);
                t1 = fmaf(s1.y, tym2[k], t1);
                t1 = fmaf(s1.x, txm2[k], t1);
                float e0 = embed_ao(t0, mask_v, row0);
                float e1 = embed_ao(t1, mask_v, row1);
                min3(best[k], e0, e1);
            }
            if (i + 1 < BODIES) { s0 = n0; s1 = n1; }
        }
        __syncthreads();
    }

    // ---- tail: resolve indices, merge 128 chunks per target, loss, atomic
    float* fv = (float*)tile;            // [32][128] values  (16 KB)
    int*   fj = (int*)tile + 32 * 128;   // [32][128] indices (16 KB)
#pragma unroll
    for (int k = 0; k < 8; ++k) {
        unsigned b = __float_as_uint(best[k]);
        int j  = (int)((b & 127u) * CHUNKS + chunk);  // j = row*128 + chunk
        int lt = g + 4 * k;
        fv[lt * CHUNKS + chunk] = __uint_as_float(b & 0xFFFFFF80u);
        fj[lt * CHUNKS + chunk] = j;
    }
    __syncthreads();

    const int tprime = tid >> 4;   // 0..31: target this 16-lane group reduces
    const int sub    = tid & 15;
    float bv = fv[tprime * CHUNKS + sub];
    int   bj = fj[tprime * CHUNKS + sub];
#pragma unroll
    for (int m = 1; m < 8; ++m) {
        float v = fv[tprime * CHUNKS + sub + 16 * m];
        int   j = fj[tprime * CHUNKS + sub + 16 * m];
        if (v < bv) { bv = v; bj = j; }
    }
#pragma unroll
    for (int s = 8; s >= 1; s >>= 1) {   // xor<16 stays in the 16-lane group
        float vv = __shfl_xor(bv, s, 64);
        int   jj = __shfl_xor(bj, s, 64);
        if (vv < bv) { bv = vv; bj = jj; }
    }
    __syncthreads();  // done reading fv/fj; safe to reuse

    if (sub == 0) {
        int tt = tbase + tprime;
        // exact loss term from the winning index (reference formula)
        float dx = src[3 * bj + 0] - tar[3 * tt + 0];
        float dy = src[3 * bj + 1] - tar[3 * tt + 1];
        float dz = src[3 * bj + 2] - tar[3 * tt + 2];
        fv[tprime] = 0.5f * fmaf(dx, dx, fmaf(dy, dy, dz * dz));
    }
    __syncthreads();
    if (tid == 0) {
        float ssum = 0.0f;
#pragma unroll
        for (int i = 0; i < 32; ++i) ssum += fv[i];
        atomicAdd(out, ssum);  // device-scope, cross-XCD safe
    }
}

extern "C" void kernel_launch(void* const* d_in, const int* in_sizes, int n_in,
                              void* d_out, int out_size, void* d_ws, size_t ws_size,
                              hipStream_t stream) {
    const float* src = (const float*)d_in[0];  // src_V [N,3] fp32
    const float* tar = (const float*)d_in[1];  // tar_V [M,3] fp32
    float* out = (float*)d_out;                // scalar loss fp32
    (void)d_ws; (void)ws_size;

    zero_out<<<1, 64, 0, stream>>>(out);
    nn7<<<BLOCKS, TPB, 0, stream>>>(src, tar, out);
}